// Round 13
// baseline (180.946 us; speedup 1.0000x reference)
//
#include <hip/hip_runtime.h>
#include <stdint.h>
#include <math.h>

// ---------------------------------------------------------------------------
// Generator_44555990728950. B=4096 molecules, N=32 nodes (chain), H=128,
// 16 GAT layers. All 32 nodes of a molecule are identical through the GAT
// stack, so: layer = relu(x + x@W + b), one class per molecule.
// R19: R18 + register prefetch + sched_barrier fence + dual MFMA chains.
//   R18 post-mortem: 87.6us, MfmaUtil 32%, VGPR=52 -- the compiler sank the
//   per-MFMA W/A loads next to their uses (register-minimizing), so each of
//   the 32 chain steps ate load latency; plus a single serial acc chain.
//   Fix (layer loop only):
//   1. prefetch W[32] (f32), A[32] (f64), residual[4], bias[4] into named
//      register arrays, compile-time indices (rule #20);
//   2. __builtin_amdgcn_sched_barrier(0) after the loads -- scheduler cannot
//      sink them back (rule #18 fence); one ~300cyc latency head per layer;
//   3. two independent acc chains (even/odd ks) -> 4 MFMA streams/SIMD at
//      2 waves/SIMD, covers dep latency up to ~256cyc at 64cyc issue.
//   ~130 VGPR live, inside the 256 cap (LDS already limits to 1 block/CU).
// Deterministic pipeline fp64 (reassociation ~1e-16); JAX partitionable
// threefry bit-exact; outputs fp32.
// ---------------------------------------------------------------------------

typedef double d4 __attribute__((ext_vector_type(4)));

struct U2 { uint32_t a, b; };

// Threefry-2x32, 20 rounds, exactly as jax._src.prng
__device__ __forceinline__ U2 threefry(uint32_t k0, uint32_t k1, uint32_t x0, uint32_t x1) {
  const uint32_t ks2 = k0 ^ k1 ^ 0x1BD11BDAu;
#define TFR(r) { x0 += x1; x1 = (x1 << (r)) | (x1 >> (32 - (r))); x1 ^= x0; }
  x0 += k0;  x1 += k1;
  TFR(13) TFR(15) TFR(26) TFR(6)
  x0 += k1;  x1 += ks2 + 1u;
  TFR(17) TFR(29) TFR(16) TFR(24)
  x0 += ks2; x1 += k0 + 2u;
  TFR(13) TFR(15) TFR(26) TFR(6)
  x0 += k0;  x1 += k1 + 3u;
  TFR(17) TFR(29) TFR(16) TFR(24)
  x0 += k1;  x1 += ks2 + 4u;
  TFR(13) TFR(15) TFR(26) TFR(6)
  x0 += ks2; x1 += k0 + 5u;
#undef TFR
  U2 r; r.a = x0; r.b = x1; return r;
}

// partitionable random_bits, 32-bit: counter = flat index; fold o1^o2
__device__ __forceinline__ uint32_t pbits(uint32_t k0, uint32_t k1, uint32_t ctr) {
  U2 r = threefry(k0, k1, 0u, ctr);
  return r.a ^ r.b;
}

__device__ __forceinline__ float bits_to_unit(uint32_t bits) {
  return __uint_as_float((bits >> 9) | 0x3f800000u) - 1.0f;  // [0,1)
}

// f32 uniform(1e-6, 1-1e-6) -> gumbel, exactly jax's f32 path
__device__ __forceinline__ float jgumbel(uint32_t k0, uint32_t k1, uint32_t ctr) {
  const float minv = 1e-6f;
  const float maxv = (float)(1.0 - 1e-6);
  const float span = maxv - minv;
  float f = bits_to_unit(pbits(k0, k1, ctr));
  float u = fmaxf(minv, __fadd_rn(__fmul_rn(f, span), minv));
  return -logf(-logf(u));
}

extern "C" __global__ void __launch_bounds__(512)
gen_kernel(const float* __restrict__ noise,
           const float* __restrict__ w1,
           const float* __restrict__ b1,
           const float* __restrict__ gat_w,
           const float* __restrict__ gat_b,
           const float* __restrict__ w_atom,
           const float* __restrict__ b_atom,
           const float* __restrict__ w_hyb,
           const float* __restrict__ b_hyb,
           const float* __restrict__ w_deg,
           const float* __restrict__ b_deg,
           const float* __restrict__ w_chg,
           const float* __restrict__ b_chg,
           const float* __restrict__ w_arom,
           const float* __restrict__ b_arom,
           const float* __restrict__ w_eex,
           const float* __restrict__ b_eex,
           const float* __restrict__ w_ety,
           const float* __restrict__ b_ety,
           float* __restrict__ out)
{
  // X[buf][col][mol], stride 18 doubles; double-buffered across layers
  __shared__ __align__(16) double sX[2][128][18];  // 36.9 KB
  __shared__ double sScr[16][16];                  // head logits, 2 KB
  __shared__ float  sNF[16][32][17];               // node features, 34.8 KB
  __shared__ double sLP[16][64];                   // lp scratch, 8 KB

  const int t       = threadIdx.x;
  const int wv      = t >> 6;                      // 0..7
  const int ln      = t & 63;
  const int g       = ln >> 4;                     // k-slice within K-tile
  const int i       = ln & 15;                     // row/col within tile
  const int molBase = blockIdx.x * 16;
  const int colb    = wv << 4;                     // wave's 16-col slice

  // ---------------- runtime D-layout probe (A/B layouts per CDNA spec)
  int rowOf[4], colOf[4];
  {
    d4 z4 = {0.0, 0.0, 0.0, 0.0};
    const double selK0 = (g == 0) ? 1.0 : 0.0;     // delta(k==0) fragment
    const double idxv  = (double)i;                // i for A-probe, j for B-probe
    d4 prow = __builtin_amdgcn_mfma_f64_16x16x4f64(idxv,  selK0, z4, 0, 0, 0);
    d4 pcol = __builtin_amdgcn_mfma_f64_16x16x4f64(selK0, idxv,  z4, 0, 0, 0);
    #pragma unroll
    for (int j = 0; j < 4; ++j) {
      rowOf[j] = (int)prow[j];
      colOf[j] = (int)pcol[j];
    }
  }

  // ---------------- stage noise transposed into sX[0][c][mol]
  #pragma unroll
  for (int it = 0; it < 4; ++it) {
    const int idx = t + (it << 9);
    const int c = idx & 127, m = idx >> 7;
    sX[0][c][m] = (double)noise[(((size_t)(molBase + m)) << 7) + c];
  }
  __syncthreads();

  // ---------------- 17 unified layers via fp64 MFMA (ping-pong buffers):
  //   l==0 : X = relu(noise @ w1 + b1)
  //   l>=1 : X = relu(X + X@W_l + b_l)
  int p = 0;
  #pragma unroll 1
  for (int l = 0; l < 17; ++l) {
    const float* __restrict__ W  = (l == 0) ? w1 : (gat_w + (((size_t)(l - 1)) << 14));
    const float* __restrict__ bp = (l == 0) ? b1 : (gat_b + ((l - 1) << 7));
    const int q = p ^ 1;

    // -------- prefetch everything into registers (compile-time indices)
    float  wr[32];
    double ar[32];
    double res[4];
    float  bj[4];
    #pragma unroll
    for (int ks = 0; ks < 32; ++ks)
      wr[ks] = W[(((ks << 2) + g) << 7) + colb + i];
    #pragma unroll
    for (int ks = 0; ks < 32; ++ks)
      ar[ks] = sX[p][(ks << 2) + g][i];
    #pragma unroll
    for (int j = 0; j < 4; ++j) {
      res[j] = sX[p][colb + colOf[j]][rowOf[j]];   // residual (unused at l==0)
      bj[j]  = bp[colb + colOf[j]];
    }
    __builtin_amdgcn_sched_barrier(0);   // loads stay ABOVE, MFMAs BELOW

    // -------- two independent accumulator chains (even / odd k-steps)
    d4 accE = {0.0, 0.0, 0.0, 0.0};
    d4 accO = {0.0, 0.0, 0.0, 0.0};
    #pragma unroll
    for (int ks = 0; ks < 32; ks += 2) {
      accE = __builtin_amdgcn_mfma_f64_16x16x4f64(ar[ks],     (double)wr[ks],     accE, 0, 0, 0);
      accO = __builtin_amdgcn_mfma_f64_16x16x4f64(ar[ks + 1], (double)wr[ks + 1], accO, 0, 0, 0);
    }

    // -------- layout-agnostic epilogue: (lane, reg j) -> (rowOf[j], colOf[j])
    #pragma unroll
    for (int j = 0; j < 4; ++j) {
      const int cc = colb + colOf[j];
      double tv = (accE[j] + accO[j]) + (double)bj[j];
      if (l > 0) tv += res[j];
      sX[q][cc][rowOf[j]] = fmax(tv, 0.0);
    }
    __syncthreads();          // new X complete; old buffer free for next layer
    p = q;
  }
  // final X is in sX[p] (p == 1 after 17 layers)

  // ---------------- phase A: head logits, 256 of 512 thr = 16 mols x 16 heads
  if (t < 256) {
    const int mh = t >> 4;             // mol 0..15
    const int h  = t & 15;             // head index
    const float* wp; int stride; double bias;
    if (h < 10)       { wp = w_atom + h;        stride = 10; bias = (double)b_atom[h]; }
    else if (h < 13)  { wp = w_hyb + (h - 10);  stride = 3;  bias = (double)b_hyb[h - 10]; }
    else if (h == 13) { wp = w_deg;             stride = 1;  bias = (double)b_deg[0]; }
    else if (h == 14) { wp = w_chg;             stride = 1;  bias = (double)b_chg[0]; }
    else              { wp = w_arom;            stride = 1;  bias = (double)b_arom[0]; }
    double acc = 0.0;
    for (int c = 0; c < 128; ++c)
      acc = fma(sX[p][c][mh], (double)wp[c * stride], acc);
    sScr[mh][h] = acc + bias;
  }
  __syncthreads();

  // partitionable split(key(42),4): child_i = threefry((0,42),(0,i))
  const U2 k0p = threefry(0u, 42u, 0u, 0u);
  const U2 k1p = threefry(0u, 42u, 0u, 1u);
  const U2 k2p = threefry(0u, 42u, 0u, 2u);
  const U2 k3p = threefry(0u, 42u, 0u, 3u);

  // ---------------- phase B: per-node sampling, 512 thr = 16 mols x 32 nodes
  {
    const int mloc = t >> 5;              // 0..15
    const int n    = t & 31;
    const int mol  = molBase + mloc;
    const double* scr = sScr[mloc];       // same logits for every node

    double m = scr[0];
    #pragma unroll
    for (int a = 1; a < 10; ++a) m = fmax(m, scr[a]);
    double lsum = 0.0;
    #pragma unroll
    for (int a = 0; a < 10; ++a) lsum += exp(scr[a] - m);
    const double lse = log(lsum);
    const uint32_t abase = ((uint32_t)mol * 32u + (uint32_t)n) * 10u;
    int asel = 0; double abest = 0.0;
    #pragma unroll
    for (int a = 0; a < 10; ++a) {
      const double gg = (double)jgumbel(k0p.a, k0p.b, abase + (uint32_t)a);
      const double sc = scr[a] + gg;
      if (a == 0 || sc > abest) { abest = sc; asel = a; }
    }
    sLP[mloc][n] = (scr[asel] - m) - lse;

    double m2 = fmax(fmax(scr[10], scr[11]), scr[12]);
    double ls2 = exp(scr[10] - m2) + exp(scr[11] - m2) + exp(scr[12] - m2);
    const double lse2 = log(ls2);
    const uint32_t hbase = ((uint32_t)mol * 32u + (uint32_t)n) * 3u;
    int hsel = 0; double hbest = 0.0;
    #pragma unroll
    for (int j = 0; j < 3; ++j) {
      const double gg = (double)jgumbel(k1p.a, k1p.b, hbase + (uint32_t)j);
      const double sc = scr[10 + j] + gg;
      if (j == 0 || sc > hbest) { hbest = sc; hsel = j; }
    }
    sLP[mloc][32 + n] = (scr[10 + hsel] - m2) - lse2;

    const double deg = 1.0 / (1.0 + exp(-scr[13]));
    const double chg = tanh(scr[14]);
    const double pr  = 1.0 / (1.0 + exp(-scr[15]));
    const uint32_t ridx = (uint32_t)mol * 32u + (uint32_t)n;
    const double uu = (double)bits_to_unit(pbits(k2p.a, k2p.b, ridx));
    const double arom = (uu < pr) ? 1.0 : 0.0;
    const double valt[10] = {4.0/5.0, 3.0/5.0, 2.0/5.0, 1.0/5.0, 4.0/5.0,
                             2.0/5.0, 6.0/5.0, 1.0/5.0, 4.0/5.0, 4.0/5.0};
    double nf[17];
    #pragma unroll
    for (int q2 = 0; q2 < 10; ++q2) nf[q2] = (q2 == asel) ? 1.0 : 0.0;
    nf[10] = deg; nf[11] = chg;
    #pragma unroll
    for (int j = 0; j < 3; ++j) nf[12 + j] = (j == hsel) ? 1.0 : 0.0;
    nf[15] = arom; nf[16] = valt[asel];

    const size_t o = ((size_t)mol * 32 + n) * 17;
    #pragma unroll
    for (int q2 = 0; q2 < 17; ++q2) {
      sNF[mloc][n][q2] = (float)nf[q2];
      out[o + q2] = (float)nf[q2];
    }
  }
  __syncthreads();

  // ---------------- phase C: lp means + edge heads; 2 rounds x 8 waves
  #pragma unroll 1
  for (int r = 0; r < 2; ++r) {
    const int mloc = (r << 3) + wv;
    const int mol  = molBase + mloc;
    if (ln == 62) {
      double sa = 0.0;
      for (int n = 0; n < 32; ++n) sa += sLP[mloc][n];
      out[2228224 + (size_t)mol] = (float)(sa / 32.0);
    } else if (ln == 63) {
      double sh = 0.0;
      for (int n = 0; n < 32; ++n) sh += sLP[mloc][32 + n];
      out[2232320 + (size_t)mol] = (float)(sh / 32.0);
    } else {
      const int e = ln;                       // 0..61
      const int nu_ = (e < 31) ? e : (e - 30);
      const int nv_ = (e < 31) ? (e + 1) : (e - 31);
      double lex = 0.0;
      double lt[4] = {0.0, 0.0, 0.0, 0.0};
      for (int q2 = 0; q2 < 17; ++q2) {
        const double f = (double)sNF[mloc][nu_][q2];
        lex = fma(f, (double)w_eex[q2], lex);
        #pragma unroll
        for (int c = 0; c < 4; ++c) lt[c] = fma(f, (double)w_ety[q2 * 4 + c], lt[c]);
      }
      for (int q2 = 0; q2 < 17; ++q2) {
        const double f = (double)sNF[mloc][nv_][q2];
        lex = fma(f, (double)w_eex[17 + q2], lex);
        #pragma unroll
        for (int c = 0; c < 4; ++c) lt[c] = fma(f, (double)w_ety[(17 + q2) * 4 + c], lt[c]);
      }
      lex += (double)b_eex[0];
      #pragma unroll
      for (int c = 0; c < 4; ++c) lt[c] += (double)b_ety[c];

      const double pex = 1.0 / (1.0 + exp(-lex));
      out[3252224 + (size_t)mol * 62 + e] = (pex > 0.5) ? 1.f : 0.f;

      const uint32_t tbase = ((uint32_t)mol * 62u + (uint32_t)e) * 4u;
      int tsel = 0; double tbest = 0.0;
      #pragma unroll
      for (int c = 0; c < 4; ++c) {
        const double gg = (double)jgumbel(k3p.a, k3p.b, tbase + (uint32_t)c);
        const double sc = lt[c] + gg;
        if (c == 0 || sc > tbest) { tbest = sc; tsel = c; }
      }
      const size_t o = 2236416 + ((size_t)mol * 62 + e) * 4;
      #pragma unroll
      for (int c = 0; c < 4; ++c) out[o + c] = (c == tsel) ? 1.f : 0.f;
    }
  }
}

extern "C" void kernel_launch(void* const* d_in, const int* in_sizes, int n_in,
                              void* d_out, int out_size, void* d_ws, size_t ws_size,
                              hipStream_t stream) {
  (void)in_sizes; (void)n_in; (void)out_size; (void)d_ws; (void)ws_size;
  hipLaunchKernelGGL(gen_kernel, dim3(256), dim3(512), 0, stream,
                     (const float*)d_in[0],  (const float*)d_in[1],
                     (const float*)d_in[2],  (const float*)d_in[3],
                     (const float*)d_in[4],
                     (const float*)d_in[7],  (const float*)d_in[8],
                     (const float*)d_in[9],  (const float*)d_in[10],
                     (const float*)d_in[11], (const float*)d_in[12],
                     (const float*)d_in[13], (const float*)d_in[14],
                     (const float*)d_in[15], (const float*)d_in[16],
                     (const float*)d_in[17], (const float*)d_in[18],
                     (const float*)d_in[19], (const float*)d_in[20],
                     (float*)d_out);
}

// Round 14
// 177.930 us; speedup vs baseline: 1.0169x; 1.0169x over previous
//
#include <hip/hip_runtime.h>
#include <stdint.h>
#include <math.h>

// ---------------------------------------------------------------------------
// Generator_44555990728950. B=4096 molecules, N=32 nodes (chain), H=128,
// 16 GAT layers. All 32 nodes of a molecule are identical through the GAT
// stack, so: layer = relu(x + x@W + b), one class per molecule.
// R20: R18 base + CROSS-LAYER W double-buffer in registers + 4 acc chains.
//   R19 post-mortem: intra-layer prefetch+sched_barrier was DEFEATED by the
//   compiler (VGPR=76 < the 96 minimum for the intended schedule; perf
//   neutral). Fix changes the DEPENDENCE STRUCTURE instead of the schedule:
//   layer l's body issues the 32 W loads of layer l+1 into wr_pre[32]
//   (no deps on layer l); the layer-end __syncthreads (vmcnt(0) drain)
//   guarantees arrival; values are loop-carried -> residency forced by
//   dataflow. Parity made compile-time by peeling layer 0 and 2x-unrolling
//   the 16 GAT layers (wr0/wr1 alternate statically). 4 independent MFMA
//   chains (8/SIMD at 2 waves/SIMD) cover dependent-chain latency. A read
//   from LDS directly in the MFMA loop (compiler emits fine-grained lgkmcnt).
// Deterministic pipeline fp64 (reassociation ~1e-16); JAX partitionable
// threefry bit-exact; outputs fp32.
// ---------------------------------------------------------------------------

typedef double d4 __attribute__((ext_vector_type(4)));

struct U2 { uint32_t a, b; };

// Threefry-2x32, 20 rounds, exactly as jax._src.prng
__device__ __forceinline__ U2 threefry(uint32_t k0, uint32_t k1, uint32_t x0, uint32_t x1) {
  const uint32_t ks2 = k0 ^ k1 ^ 0x1BD11BDAu;
#define TFR(r) { x0 += x1; x1 = (x1 << (r)) | (x1 >> (32 - (r))); x1 ^= x0; }
  x0 += k0;  x1 += k1;
  TFR(13) TFR(15) TFR(26) TFR(6)
  x0 += k1;  x1 += ks2 + 1u;
  TFR(17) TFR(29) TFR(16) TFR(24)
  x0 += ks2; x1 += k0 + 2u;
  TFR(13) TFR(15) TFR(26) TFR(6)
  x0 += k0;  x1 += k1 + 3u;
  TFR(17) TFR(29) TFR(16) TFR(24)
  x0 += k1;  x1 += ks2 + 4u;
  TFR(13) TFR(15) TFR(26) TFR(6)
  x0 += ks2; x1 += k0 + 5u;
#undef TFR
  U2 r; r.a = x0; r.b = x1; return r;
}

// partitionable random_bits, 32-bit: counter = flat index; fold o1^o2
__device__ __forceinline__ uint32_t pbits(uint32_t k0, uint32_t k1, uint32_t ctr) {
  U2 r = threefry(k0, k1, 0u, ctr);
  return r.a ^ r.b;
}

__device__ __forceinline__ float bits_to_unit(uint32_t bits) {
  return __uint_as_float((bits >> 9) | 0x3f800000u) - 1.0f;  // [0,1)
}

// f32 uniform(1e-6, 1-1e-6) -> gumbel, exactly jax's f32 path
__device__ __forceinline__ float jgumbel(uint32_t k0, uint32_t k1, uint32_t ctr) {
  const float minv = 1e-6f;
  const float maxv = (float)(1.0 - 1e-6);
  const float span = maxv - minv;
  float f = bits_to_unit(pbits(k0, k1, ctr));
  float u = fmaxf(minv, __fadd_rn(__fmul_rn(f, span), minv));
  return -logf(-logf(u));
}

extern "C" __global__ void __launch_bounds__(512)
gen_kernel(const float* __restrict__ noise,
           const float* __restrict__ w1,
           const float* __restrict__ b1,
           const float* __restrict__ gat_w,
           const float* __restrict__ gat_b,
           const float* __restrict__ w_atom,
           const float* __restrict__ b_atom,
           const float* __restrict__ w_hyb,
           const float* __restrict__ b_hyb,
           const float* __restrict__ w_deg,
           const float* __restrict__ b_deg,
           const float* __restrict__ w_chg,
           const float* __restrict__ b_chg,
           const float* __restrict__ w_arom,
           const float* __restrict__ b_arom,
           const float* __restrict__ w_eex,
           const float* __restrict__ b_eex,
           const float* __restrict__ w_ety,
           const float* __restrict__ b_ety,
           float* __restrict__ out)
{
  // X[buf][col][mol], stride 18 doubles; double-buffered across layers
  __shared__ __align__(16) double sX[2][128][18];  // 36.9 KB
  __shared__ double sScr[16][16];                  // head logits, 2 KB
  __shared__ float  sNF[16][32][17];               // node features, 34.8 KB
  __shared__ double sLP[16][64];                   // lp scratch, 8 KB

  const int t       = threadIdx.x;
  const int wv      = t >> 6;                      // 0..7
  const int ln      = t & 63;
  const int g       = ln >> 4;                     // k-slice within K-tile
  const int i       = ln & 15;                     // row/col within tile
  const int molBase = blockIdx.x * 16;
  const int colb    = wv << 4;                     // wave's 16-col slice

  // ---------------- runtime D-layout probe (A/B layouts per CDNA spec)
  int rowOf[4], colOf[4];
  {
    d4 z4 = {0.0, 0.0, 0.0, 0.0};
    const double selK0 = (g == 0) ? 1.0 : 0.0;     // delta(k==0) fragment
    const double idxv  = (double)i;                // i for A-probe, j for B-probe
    d4 prow = __builtin_amdgcn_mfma_f64_16x16x4f64(idxv,  selK0, z4, 0, 0, 0);
    d4 pcol = __builtin_amdgcn_mfma_f64_16x16x4f64(selK0, idxv,  z4, 0, 0, 0);
    #pragma unroll
    for (int j = 0; j < 4; ++j) {
      rowOf[j] = (int)prow[j];
      colOf[j] = (int)pcol[j];
    }
  }

  // W register double-buffer (loop-carried across layers)
  float wr0[32], wr1[32];

  // pre-loop: W for layer 0 (w1) -> wr0  (overlaps noise staging)
  #pragma unroll
  for (int ks = 0; ks < 32; ++ks)
    wr0[ks] = w1[(((ks << 2) + g) << 7) + colb + i];

  // ---------------- stage noise transposed into sX[0][c][mol]
  #pragma unroll
  for (int it = 0; it < 4; ++it) {
    const int idx = t + (it << 9);
    const int c = idx & 127, m = idx >> 7;
    sX[0][c][m] = (double)noise[(((size_t)(molBase + m)) << 7) + c];
  }
  __syncthreads();

  int p = 0;

  // One layer: use W from WUSE regs, prefetch nextW into WPRE, MFMA, epilogue.
  // The end-of-layer __syncthreads (vmcnt(0) drain) guarantees WPRE arrival.
#define LAYERSTEP(WUSE, WPRE, nextWptr, bptr, ISFIRST)                          \
  {                                                                             \
    const int q = p ^ 1;                                                        \
    const float* __restrict__ nW = (nextWptr);                                  \
    _Pragma("unroll")                                                           \
    for (int ks = 0; ks < 32; ++ks)                                             \
      WPRE[ks] = nW[(((ks << 2) + g) << 7) + colb + i];                         \
    d4 ac0 = {0.0,0.0,0.0,0.0}, ac1 = {0.0,0.0,0.0,0.0};                        \
    d4 ac2 = {0.0,0.0,0.0,0.0}, ac3 = {0.0,0.0,0.0,0.0};                        \
    _Pragma("unroll")                                                           \
    for (int ks = 0; ks < 32; ks += 4) {                                        \
      ac0 = __builtin_amdgcn_mfma_f64_16x16x4f64(sX[p][((ks + 0) << 2) + g][i], \
            (double)WUSE[ks + 0], ac0, 0, 0, 0);                                \
      ac1 = __builtin_amdgcn_mfma_f64_16x16x4f64(sX[p][((ks + 1) << 2) + g][i], \
            (double)WUSE[ks + 1], ac1, 0, 0, 0);                                \
      ac2 = __builtin_amdgcn_mfma_f64_16x16x4f64(sX[p][((ks + 2) << 2) + g][i], \
            (double)WUSE[ks + 2], ac2, 0, 0, 0);                                \
      ac3 = __builtin_amdgcn_mfma_f64_16x16x4f64(sX[p][((ks + 3) << 2) + g][i], \
            (double)WUSE[ks + 3], ac3, 0, 0, 0);                                \
    }                                                                           \
    _Pragma("unroll")                                                           \
    for (int j = 0; j < 4; ++j) {                                               \
      const int cc = colb + colOf[j];                                           \
      double tv = ((ac0[j] + ac1[j]) + (ac2[j] + ac3[j])) + (double)(bptr)[cc]; \
      if (!(ISFIRST)) tv += sX[p][cc][rowOf[j]];                                \
      sX[q][cc][rowOf[j]] = fmax(tv, 0.0);                                      \
    }                                                                           \
    __syncthreads();                                                            \
    p = q;                                                                      \
  }

  // peel layer 0 (w1/b1, no residual); prefetch GAT layer 0 into wr1
  LAYERSTEP(wr0, wr1, gat_w, b1, 1)

  // 16 GAT layers, 2 per iteration (static wr0/wr1 parity)
  #pragma unroll 1
  for (int li = 0; li < 8; ++li) {
    const int lA = 2 * li;                         // GAT layer for step 1
    const int lB = 2 * li + 1;                     // GAT layer for step 2
    const int pfA = lB;                            // prefetch for step 1
    const int pfB = (lB + 1 < 16) ? (lB + 1) : 15; // clamped dummy at the end
    LAYERSTEP(wr1, wr0, gat_w + ((size_t)pfA << 14), gat_b + (lA << 7), 0)
    LAYERSTEP(wr0, wr1, gat_w + ((size_t)pfB << 14), gat_b + (lB << 7), 0)
  }
#undef LAYERSTEP
  // final X is in sX[p] (p == 1 after 17 layers)

  // ---------------- phase A: head logits, 256 of 512 thr = 16 mols x 16 heads
  if (t < 256) {
    const int mh = t >> 4;             // mol 0..15
    const int h  = t & 15;             // head index
    const float* wp; int stride; double bias;
    if (h < 10)       { wp = w_atom + h;        stride = 10; bias = (double)b_atom[h]; }
    else if (h < 13)  { wp = w_hyb + (h - 10);  stride = 3;  bias = (double)b_hyb[h - 10]; }
    else if (h == 13) { wp = w_deg;             stride = 1;  bias = (double)b_deg[0]; }
    else if (h == 14) { wp = w_chg;             stride = 1;  bias = (double)b_chg[0]; }
    else              { wp = w_arom;            stride = 1;  bias = (double)b_arom[0]; }
    double acc = 0.0;
    for (int c = 0; c < 128; ++c)
      acc = fma(sX[p][c][mh], (double)wp[c * stride], acc);
    sScr[mh][h] = acc + bias;
  }
  __syncthreads();

  // partitionable split(key(42),4): child_i = threefry((0,42),(0,i))
  const U2 k0p = threefry(0u, 42u, 0u, 0u);
  const U2 k1p = threefry(0u, 42u, 0u, 1u);
  const U2 k2p = threefry(0u, 42u, 0u, 2u);
  const U2 k3p = threefry(0u, 42u, 0u, 3u);

  // ---------------- phase B: per-node sampling, 512 thr = 16 mols x 32 nodes
  {
    const int mloc = t >> 5;              // 0..15
    const int n    = t & 31;
    const int mol  = molBase + mloc;
    const double* scr = sScr[mloc];       // same logits for every node

    double m = scr[0];
    #pragma unroll
    for (int a = 1; a < 10; ++a) m = fmax(m, scr[a]);
    double lsum = 0.0;
    #pragma unroll
    for (int a = 0; a < 10; ++a) lsum += exp(scr[a] - m);
    const double lse = log(lsum);
    const uint32_t abase = ((uint32_t)mol * 32u + (uint32_t)n) * 10u;
    int asel = 0; double abest = 0.0;
    #pragma unroll
    for (int a = 0; a < 10; ++a) {
      const double gg = (double)jgumbel(k0p.a, k0p.b, abase + (uint32_t)a);
      const double sc = scr[a] + gg;
      if (a == 0 || sc > abest) { abest = sc; asel = a; }
    }
    sLP[mloc][n] = (scr[asel] - m) - lse;

    double m2 = fmax(fmax(scr[10], scr[11]), scr[12]);
    double ls2 = exp(scr[10] - m2) + exp(scr[11] - m2) + exp(scr[12] - m2);
    const double lse2 = log(ls2);
    const uint32_t hbase = ((uint32_t)mol * 32u + (uint32_t)n) * 3u;
    int hsel = 0; double hbest = 0.0;
    #pragma unroll
    for (int j = 0; j < 3; ++j) {
      const double gg = (double)jgumbel(k1p.a, k1p.b, hbase + (uint32_t)j);
      const double sc = scr[10 + j] + gg;
      if (j == 0 || sc > hbest) { hbest = sc; hsel = j; }
    }
    sLP[mloc][32 + n] = (scr[10 + hsel] - m2) - lse2;

    const double deg = 1.0 / (1.0 + exp(-scr[13]));
    const double chg = tanh(scr[14]);
    const double pr  = 1.0 / (1.0 + exp(-scr[15]));
    const uint32_t ridx = (uint32_t)mol * 32u + (uint32_t)n;
    const double uu = (double)bits_to_unit(pbits(k2p.a, k2p.b, ridx));
    const double arom = (uu < pr) ? 1.0 : 0.0;
    const double valt[10] = {4.0/5.0, 3.0/5.0, 2.0/5.0, 1.0/5.0, 4.0/5.0,
                             2.0/5.0, 6.0/5.0, 1.0/5.0, 4.0/5.0, 4.0/5.0};
    double nf[17];
    #pragma unroll
    for (int q2 = 0; q2 < 10; ++q2) nf[q2] = (q2 == asel) ? 1.0 : 0.0;
    nf[10] = deg; nf[11] = chg;
    #pragma unroll
    for (int j = 0; j < 3; ++j) nf[12 + j] = (j == hsel) ? 1.0 : 0.0;
    nf[15] = arom; nf[16] = valt[asel];

    const size_t o = ((size_t)mol * 32 + n) * 17;
    #pragma unroll
    for (int q2 = 0; q2 < 17; ++q2) {
      sNF[mloc][n][q2] = (float)nf[q2];
      out[o + q2] = (float)nf[q2];
    }
  }
  __syncthreads();

  // ---------------- phase C: lp means + edge heads; 2 rounds x 8 waves
  #pragma unroll 1
  for (int r = 0; r < 2; ++r) {
    const int mloc = (r << 3) + wv;
    const int mol  = molBase + mloc;
    if (ln == 62) {
      double sa = 0.0;
      for (int n = 0; n < 32; ++n) sa += sLP[mloc][n];
      out[2228224 + (size_t)mol] = (float)(sa / 32.0);
    } else if (ln == 63) {
      double sh = 0.0;
      for (int n = 0; n < 32; ++n) sh += sLP[mloc][32 + n];
      out[2232320 + (size_t)mol] = (float)(sh / 32.0);
    } else {
      const int e = ln;                       // 0..61
      const int nu_ = (e < 31) ? e : (e - 30);
      const int nv_ = (e < 31) ? (e + 1) : (e - 31);
      double lex = 0.0;
      double lt[4] = {0.0, 0.0, 0.0, 0.0};
      for (int q2 = 0; q2 < 17; ++q2) {
        const double f = (double)sNF[mloc][nu_][q2];
        lex = fma(f, (double)w_eex[q2], lex);
        #pragma unroll
        for (int c = 0; c < 4; ++c) lt[c] = fma(f, (double)w_ety[q2 * 4 + c], lt[c]);
      }
      for (int q2 = 0; q2 < 17; ++q2) {
        const double f = (double)sNF[mloc][nv_][q2];
        lex = fma(f, (double)w_eex[17 + q2], lex);
        #pragma unroll
        for (int c = 0; c < 4; ++c) lt[c] = fma(f, (double)w_ety[(17 + q2) * 4 + c], lt[c]);
      }
      lex += (double)b_eex[0];
      #pragma unroll
      for (int c = 0; c < 4; ++c) lt[c] += (double)b_ety[c];

      const double pex = 1.0 / (1.0 + exp(-lex));
      out[3252224 + (size_t)mol * 62 + e] = (pex > 0.5) ? 1.f : 0.f;

      const uint32_t tbase = ((uint32_t)mol * 62u + (uint32_t)e) * 4u;
      int tsel = 0; double tbest = 0.0;
      #pragma unroll
      for (int c = 0; c < 4; ++c) {
        const double gg = (double)jgumbel(k3p.a, k3p.b, tbase + (uint32_t)c);
        const double sc = lt[c] + gg;
        if (c == 0 || sc > tbest) { tbest = sc; tsel = c; }
      }
      const size_t o = 2236416 + ((size_t)mol * 62 + e) * 4;
      #pragma unroll
      for (int c = 0; c < 4; ++c) out[o + c] = (c == tsel) ? 1.f : 0.f;
    }
  }
}

extern "C" void kernel_launch(void* const* d_in, const int* in_sizes, int n_in,
                              void* d_out, int out_size, void* d_ws, size_t ws_size,
                              hipStream_t stream) {
  (void)in_sizes; (void)n_in; (void)out_size; (void)d_ws; (void)ws_size;
  hipLaunchKernelGGL(gen_kernel, dim3(256), dim3(512), 0, stream,
                     (const float*)d_in[0],  (const float*)d_in[1],
                     (const float*)d_in[2],  (const float*)d_in[3],
                     (const float*)d_in[4],
                     (const float*)d_in[7],  (const float*)d_in[8],
                     (const float*)d_in[9],  (const float*)d_in[10],
                     (const float*)d_in[11], (const float*)d_in[12],
                     (const float*)d_in[13], (const float*)d_in[14],
                     (const float*)d_in[15], (const float*)d_in[16],
                     (const float*)d_in[17], (const float*)d_in[18],
                     (const float*)d_in[19], (const float*)d_in[20],
                     (float*)d_out);
}